// Round 16
// baseline (106.190 us; speedup 1.0000x reference)
//
#include <hip/hip_runtime.h>

// NeighbourCovariance: V=200000, C=3, F=16, K=32
// out[v] = [cov_flat (F*6=96), mean_flat (F*3=48)] -> 144 f32 per vertex.
//
// Ledger:
//  R3: NT stores banned (3x write amplification).
//  R5-R7: fp16 -> u8 -> fused record: 131 -> 115 -> 98 us.
//  R10: HBM bytes ~free. R13: line-visits are the slope (26us per
//       6.4M lines). R12: 1 line/neighbor floor: 89 us.
//  R14: 2 lanes/vertex: VGPR 256, occ 9.6%, 197 us. REVERTED.
//  R15: packed f32 accums: 87 us, VGPR 36. VALU issue ~11us only ->
//       intercept (~63us) is mostly UNCOVERED VMCNT STALL: at VGPR 36
//       the compiler keeps ~2 gathers in flight, wave alternates
//       issue->stall->compute.
//  R16: register double-buffer (2 x 8 records ping-pong): compute(A)
//       covers loads(B) latency and vice versa. sched_barrier(0) after
//       each load group. VGPR ~120 -> 4 waves/SIMD (vs R14's 1: ok).

#define EPS 1e-6f

constexpr int C_DIM = 3;
constexpr int F_DIM = 16;
constexpr int K_N = 32;
constexpr int V_PER_BLOCK = 64;   // 256 threads, 4 threads/vertex
constexpr int THREADS = 256;
constexpr int BATCH = 8;
constexpr int REC_DW = 8;         // 32B record

typedef float v4f __attribute__((ext_vector_type(4)));
typedef float v2f __attribute__((ext_vector_type(2)));
typedef unsigned int u32;
typedef u32 v4u __attribute__((ext_vector_type(4)));
typedef _Float16 h2 __attribute__((ext_vector_type(2)));

static __device__ inline void unpack_h2(u32 u, float& a, float& b) {
  h2 hv = __builtin_bit_cast(h2, u);
  a = (float)hv.x;
  b = (float)hv.y;
}

// ---------------------------------------------------------------------------
// Prepass: rec[V] (32B): [q0, cxy, q1, cz | q2, cxy, q3, cz]
//   q_j = u8 feats 4j..4j+3 (x255); cxy = fp16 x|y; cz = fp16 z|0.
//   Coords duplicated in both 16B halves. Lane t: half (t>>1), word (t&1).
// ---------------------------------------------------------------------------
__global__ __launch_bounds__(256) void pack_rec_kernel(
    const float* __restrict__ coords,
    const float* __restrict__ feats,
    u32* __restrict__ rec,
    int V)
{
  int v = blockIdx.x * blockDim.x + threadIdx.x;
  if (v >= V) return;

  u32 q[4];
  #pragma unroll
  for (int i = 0; i < 4; ++i) {
    const v4f f = *reinterpret_cast<const v4f*>(feats + (size_t)v * F_DIM + i * 4);
    u32 b0 = (u32)__float2int_rn(fminf(fmaxf(f.x, 0.f), 1.f) * 255.f);
    u32 b1 = (u32)__float2int_rn(fminf(fmaxf(f.y, 0.f), 1.f) * 255.f);
    u32 b2 = (u32)__float2int_rn(fminf(fmaxf(f.z, 0.f), 1.f) * 255.f);
    u32 b3 = (u32)__float2int_rn(fminf(fmaxf(f.w, 0.f), 1.f) * 255.f);
    q[i] = b0 | (b1 << 8) | (b2 << 16) | (b3 << 24);
  }
  h2 cxy, cz;
  cxy.x = (_Float16)coords[(size_t)v * 3 + 0];
  cxy.y = (_Float16)coords[(size_t)v * 3 + 1];
  cz.x  = (_Float16)coords[(size_t)v * 3 + 2];
  cz.y  = (_Float16)0.f;
  const u32 uxy = __builtin_bit_cast(u32, cxy);
  const u32 uz  = __builtin_bit_cast(u32, cz);

  u32* dst = rec + (size_t)v * REC_DW;
  v4u lo, hi;
  lo.x = q[0]; lo.y = uxy; lo.z = q[1]; lo.w = uz;   // half 0: quads 0,1
  hi.x = q[2]; hi.y = uxy; hi.z = q[3]; hi.w = uz;   // half 1: quads 2,3
  *reinterpret_cast<v4u*>(dst + 0) = lo;
  *reinterpret_cast<v4u*>(dst + 4) = hi;
}

// ---------------------------------------------------------------------------
// Main kernel: ONE dwordx4 gather per neighbor per lane; packed-f32 accums;
// 2x8 register double-buffer pipeline.
// ---------------------------------------------------------------------------
__global__ __launch_bounds__(THREADS) void neigh_cov_r_kernel(
    const u32* __restrict__ rec,    // [V*8]
    const int* __restrict__ nidx,   // [V,32]
    float* __restrict__ out,        // [V,144]
    int V)
{
  __shared__ int sidx[V_PER_BLOCK][K_N + 1];   // stride 33: conflict-free

  const int tid = threadIdx.x;
  const int block_v0 = blockIdx.x * V_PER_BLOCK;

  {
    const long long base = (long long)block_v0 * K_N;
    const long long avail = (long long)V * K_N - base;
    #pragma unroll
    for (int i = tid; i < V_PER_BLOCK * K_N; i += THREADS) {
      int val = (i < avail) ? __builtin_nontemporal_load(nidx + base + i) : 0;
      sidx[i / K_N][i % K_N] = val;
    }
  }
  __syncthreads();

  const int vloc = tid >> 2;        // vertex within block
  const int t    = tid & 3;         // feature quad owner
  const int v    = block_v0 + vloc;
  if (v >= V) return;

  const int half_off = (t >> 1) * 4;  // 16B half holding my quad
  const bool hi_word = (t & 1);       // word within the half: .x or .z

  v2f a0[4], a1[4], a2[4], a3[4], a4[4];
  #pragma unroll
  for (int j = 0; j < 4; ++j) {
    a0[j] = (v2f){0.f, 0.f};
    a1[j] = (v2f){0.f, 0.f};
    a2[j] = (v2f){0.f, 0.f};
    a3[j] = (v2f){0.f, 0.f};
    a4[j] = (v2f){0.f, 0.f};
  }

  v4u bA[BATCH], bB[BATCH];

  auto LOADB = [&](v4u* buf, int kb) {
    #pragma unroll
    for (int u = 0; u < BATCH; ++u) {
      const int idx = sidx[vloc][kb + u];
      buf[u] = *reinterpret_cast<const v4u*>(rec + (size_t)idx * REC_DW + half_off);
    }
  };

  auto COMP = [&](const v4u* buf) {
    #pragma unroll
    for (int u = 0; u < BATCH; ++u) {
      float x0, x1, x2, zpad;
      unpack_h2(buf[u].y, x0, x1);
      unpack_h2(buf[u].w, x2, zpad);

      const v2f p0 = {1.0f, x0};
      const v2f p1 = {x1, x2};
      const v2f p2 = (v2f){x0, x1} * (v2f){x0, x0};   // (xx00, xx10)
      const v2f p3 = (v2f){x1, x2} * (v2f){x1, x0};   // (xx11, xx20)
      const v2f p4 = (v2f){x2, x2} * (v2f){x1, x2};   // (xx21, xx22)

      const u32 q = hi_word ? buf[u].z : buf[u].x;
      const float wv[4] = {(float)(q & 0xffu), (float)((q >> 8) & 0xffu),
                           (float)((q >> 16) & 0xffu), (float)(q >> 24)};
      #pragma unroll
      for (int j = 0; j < 4; ++j) {
        const v2f w2 = {wv[j], wv[j]};
        a0[j] = w2 * p0 + a0[j];   // v_pk_fma_f32
        a1[j] = w2 * p1 + a1[j];
        a2[j] = w2 * p2 + a2[j];
        a3[j] = w2 * p3 + a3[j];
        a4[j] = w2 * p4 + a4[j];
      }
    }
  };

  // Software pipeline: compute(X) covers the in-flight loads of the other
  // buffer. sched_barrier(0) pins each load group to issue before the next
  // compute phase's instructions.
  LOADB(bA, 0);
  LOADB(bB, 8);
  __builtin_amdgcn_sched_barrier(0);
  COMP(bA);
  LOADB(bA, 16);
  __builtin_amdgcn_sched_barrier(0);
  COMP(bB);
  LOADB(bB, 24);
  __builtin_amdgcn_sched_barrier(0);
  COMP(bA);
  COMP(bB);

  // Epilogue. Raw counts: s = 255*wsum; iw scale cancels with EPS*255.
  float cov[24];
  float mn[12];
  #pragma unroll
  for (int j = 0; j < 4; ++j) {
    const float s   = a0[j].x;
    const float wx0 = a0[j].y;
    const float wx1 = a1[j].x;
    const float wx2 = a1[j].y;
    const float e00 = a2[j].x;
    const float e10 = a2[j].y;
    const float e11 = a3[j].x;
    const float e20 = a3[j].y;
    const float e21 = a4[j].x;
    const float e22 = a4[j].y;
    const float iw = 1.0f / (s + 255.0f * EPS);
    const float m0 = wx0 * iw;
    const float m1 = wx1 * iw;
    const float m2 = wx2 * iw;
    cov[j * 6 + 0] = fmaf(-m0, m0, e00 * iw);
    cov[j * 6 + 1] = fmaf(-m1, m0, e10 * iw);
    cov[j * 6 + 2] = fmaf(-m1, m1, e11 * iw);
    cov[j * 6 + 3] = fmaf(-m2, m0, e20 * iw);
    cov[j * 6 + 4] = fmaf(-m2, m1, e21 * iw);
    cov[j * 6 + 5] = fmaf(-m2, m2, e22 * iw);
    mn[j * 3 + 0] = m0;
    mn[j * 3 + 1] = m1;
    mn[j * 3 + 2] = m2;
  }

  // Normal cached float4 stores (L2 write-combines). All 16B-aligned.
  float* outv = out + (size_t)v * 144;
  v4f* cdst = reinterpret_cast<v4f*>(outv + t * 24);       // 24 floats
  const v4f* csrc = reinterpret_cast<const v4f*>(cov);
  #pragma unroll
  for (int q2 = 0; q2 < 6; ++q2) cdst[q2] = csrc[q2];
  v4f* mdst = reinterpret_cast<v4f*>(outv + 96 + t * 12);  // 12 floats
  const v4f* msrc = reinterpret_cast<const v4f*>(mn);
  #pragma unroll
  for (int q2 = 0; q2 < 3; ++q2) mdst[q2] = msrc[q2];
}

// ---------------------------------------------------------------------------
// Fallback (no workspace): f32 path, R1 structure.
// ---------------------------------------------------------------------------
__global__ __launch_bounds__(THREADS) void neigh_cov_f_kernel(
    const float* __restrict__ coords,
    const float* __restrict__ feats,
    const int*   __restrict__ nidx,
    float*       __restrict__ out,
    int V)
{
  __shared__ int sidx[V_PER_BLOCK][K_N + 1];
  const int tid = threadIdx.x;
  const int block_v0 = blockIdx.x * V_PER_BLOCK;
  {
    const long long base = (long long)block_v0 * K_N;
    const long long avail = (long long)V * K_N - base;
    for (int i = tid; i < V_PER_BLOCK * K_N; i += THREADS) {
      int val = (i < avail) ? nidx[base + i] : 0;
      sidx[i / K_N][i % K_N] = val;
    }
  }
  __syncthreads();
  const int vloc = tid >> 2, t = tid & 3;
  const int v = block_v0 + vloc;
  if (v >= V) return;
  float s[4] = {0,0,0,0}, wx0[4] = {0,0,0,0}, wx1[4] = {0,0,0,0}, wx2[4] = {0,0,0,0};
  float e00[4] = {0,0,0,0}, e10[4] = {0,0,0,0}, e11[4] = {0,0,0,0};
  float e20[4] = {0,0,0,0}, e21[4] = {0,0,0,0}, e22[4] = {0,0,0,0};
  #pragma unroll 4
  for (int k = 0; k < K_N; ++k) {
    const int idx = sidx[vloc][k];
    const v4f w4 = *reinterpret_cast<const v4f*>(feats + (size_t)idx * F_DIM + t * 4);
    const float x0 = coords[(size_t)idx * C_DIM + 0];
    const float x1 = coords[(size_t)idx * C_DIM + 1];
    const float x2 = coords[(size_t)idx * C_DIM + 2];
    const float xx00 = x0*x0, xx10 = x1*x0, xx11 = x1*x1;
    const float xx20 = x2*x0, xx21 = x2*x1, xx22 = x2*x2;
    const float wv[4] = {w4.x, w4.y, w4.z, w4.w};
    #pragma unroll
    for (int j = 0; j < 4; ++j) {
      const float w = wv[j];
      s[j] += w;
      wx0[j] = fmaf(w, x0, wx0[j]); wx1[j] = fmaf(w, x1, wx1[j]); wx2[j] = fmaf(w, x2, wx2[j]);
      e00[j] = fmaf(w, xx00, e00[j]); e10[j] = fmaf(w, xx10, e10[j]); e11[j] = fmaf(w, xx11, e11[j]);
      e20[j] = fmaf(w, xx20, e20[j]); e21[j] = fmaf(w, xx21, e21[j]); e22[j] = fmaf(w, xx22, e22[j]);
    }
  }
  float cov[24], mn[12];
  #pragma unroll
  for (int j = 0; j < 4; ++j) {
    const float iw = 1.0f / (s[j] + EPS);
    const float m0 = wx0[j]*iw, m1 = wx1[j]*iw, m2 = wx2[j]*iw;
    cov[j*6+0] = fmaf(-m0, m0, e00[j]*iw);
    cov[j*6+1] = fmaf(-m1, m0, e10[j]*iw);
    cov[j*6+2] = fmaf(-m1, m1, e11[j]*iw);
    cov[j*6+3] = fmaf(-m2, m0, e20[j]*iw);
    cov[j*6+4] = fmaf(-m2, m1, e21[j]*iw);
    cov[j*6+5] = fmaf(-m2, m2, e22[j]*iw);
    mn[j*3+0] = m0; mn[j*3+1] = m1; mn[j*3+2] = m2;
  }
  float* outv = out + (size_t)v * 144;
  v4f* cdst = reinterpret_cast<v4f*>(outv + t * 24);
  const v4f* csrc = reinterpret_cast<const v4f*>(cov);
  #pragma unroll
  for (int q = 0; q < 6; ++q) cdst[q] = csrc[q];
  v4f* mdst = reinterpret_cast<v4f*>(outv + 96 + t * 12);
  const v4f* msrc = reinterpret_cast<const v4f*>(mn);
  #pragma unroll
  for (int q = 0; q < 3; ++q) mdst[q] = msrc[q];
}

extern "C" void kernel_launch(void* const* d_in, const int* in_sizes, int n_in,
                              void* d_out, int out_size, void* d_ws, size_t ws_size,
                              hipStream_t stream) {
  const float* coords = (const float*)d_in[0];
  const float* feats  = (const float*)d_in[1];
  const int*   nidx   = (const int*)d_in[2];
  float* out = (float*)d_out;

  const int V = in_sizes[0] / C_DIM;   // 200000
  const int blocks = (V + V_PER_BLOCK - 1) / V_PER_BLOCK;

  const size_t rec_bytes = (size_t)V * REC_DW * 4;   // 6.4 MB
  const bool use_rec = (d_ws != nullptr) && (ws_size >= rec_bytes);

  if (use_rec) {
    u32* rec = (u32*)d_ws;
    pack_rec_kernel<<<(V + 255) / 256, 256, 0, stream>>>(coords, feats, rec, V);
    neigh_cov_r_kernel<<<blocks, THREADS, 0, stream>>>(rec, nidx, out, V);
  } else {
    neigh_cov_f_kernel<<<blocks, THREADS, 0, stream>>>(coords, feats, nidx, out, V);
  }
}

// Round 17
// 95.195 us; speedup vs baseline: 1.1155x; 1.1155x over previous
//
#include <hip/hip_runtime.h>

// NeighbourCovariance: V=200000, C=3, F=16, K=32
// out[v] = [cov_flat (F*6=96), mean_flat (F*3=48)] -> 144 f32 per vertex.
//
// Ledger:
//  R3: NT stores banned (3x write amplification).
//  R5-R7: fp16 -> u8 -> fused record: 131 -> 115 -> 98 us.
//  R10: HBM bytes ~free. R13: line-visits are the slope (~26us/6.4M).
//  R12: 1 line-visit/neighbor floor: 89 us.
//  R14/R16: occupancy-for-pipeline trades LOSE (197 / 97 us). TLP via
//       wave count is the latency cover; keep VGPR <= ~40.
//  R15: packed-f32 accums, VGPR 36, occ 58%: 87 us main. BEST.
//       Balance: VALU 34%, TA ~30%, HBM 44% - nothing saturated.
//  R17: coalesced prepass (was ~9us: 64B-stride feat reads) + 128-thread
//       main blocks (finer packing). Main kernel unchanged from R15.

#define EPS 1e-6f

constexpr int C_DIM = 3;
constexpr int F_DIM = 16;
constexpr int K_N = 32;
constexpr int V_PER_BLOCK = 32;   // 128 threads, 4 threads/vertex
constexpr int THREADS = 128;
constexpr int BATCH = 8;
constexpr int REC_DW = 8;         // 32B record

typedef float v4f __attribute__((ext_vector_type(4)));
typedef float v2f __attribute__((ext_vector_type(2)));
typedef unsigned int u32;
typedef u32 v4u __attribute__((ext_vector_type(4)));
typedef u32 v2u __attribute__((ext_vector_type(2)));
typedef _Float16 h2 __attribute__((ext_vector_type(2)));

static __device__ inline void unpack_h2(u32 u, float& a, float& b) {
  h2 hv = __builtin_bit_cast(h2, u);
  a = (float)hv.x;
  b = (float)hv.y;
}

static __device__ inline u32 quant_quad(v4f f) {
  u32 b0 = (u32)__float2int_rn(fminf(fmaxf(f.x, 0.f), 1.f) * 255.f);
  u32 b1 = (u32)__float2int_rn(fminf(fmaxf(f.y, 0.f), 1.f) * 255.f);
  u32 b2 = (u32)__float2int_rn(fminf(fmaxf(f.z, 0.f), 1.f) * 255.f);
  u32 b3 = (u32)__float2int_rn(fminf(fmaxf(f.w, 0.f), 1.f) * 255.f);
  return b0 | (b1 << 8) | (b2 << 16) | (b3 << 24);
}

// ---------------------------------------------------------------------------
// Prepass (coalesced): 256 threads = 64 vertices x 4 lanes. Lane t loads
// feats[v*16+t*4] (quad-coalesced 64B), quantizes its quad, and writes its
// uint2 pair of the record: t=0:(q0,cxy) t=1:(q1,cz) t=2:(q2,cxy) t=3:(q3,cz)
// -> rec dwords [q0,cxy,q1,cz,q2,cxy,q3,cz], 8B/lane coalesced stores.
// ---------------------------------------------------------------------------
__global__ __launch_bounds__(256) void pack_rec_kernel(
    const float* __restrict__ coords,
    const float* __restrict__ feats,
    u32* __restrict__ rec,
    int V)
{
  const int tid = threadIdx.x;
  const int v = blockIdx.x * 64 + (tid >> 2);
  const int t = tid & 3;
  if (v >= V) return;

  const v4f f = *reinterpret_cast<const v4f*>(feats + (size_t)v * F_DIM + t * 4);
  const u32 q = quant_quad(f);

  u32 cw;
  if ((t & 1) == 0) {           // even lanes carry cxy
    h2 cxy;
    cxy.x = (_Float16)coords[(size_t)v * 3 + 0];
    cxy.y = (_Float16)coords[(size_t)v * 3 + 1];
    cw = __builtin_bit_cast(u32, cxy);
  } else {                      // odd lanes carry cz
    h2 cz;
    cz.x = (_Float16)coords[(size_t)v * 3 + 2];
    cz.y = (_Float16)0.f;
    cw = __builtin_bit_cast(u32, cz);
  }

  v2u pair;
  pair.x = q;
  pair.y = cw;
  *reinterpret_cast<v2u*>(rec + (size_t)v * REC_DW + t * 2) = pair;
}

// ---------------------------------------------------------------------------
// Main kernel (R15 unchanged, 128-thread blocks): ONE dwordx4 gather per
// neighbor per lane; packed-f32 accums.
// ---------------------------------------------------------------------------
__global__ __launch_bounds__(THREADS) void neigh_cov_r_kernel(
    const u32* __restrict__ rec,    // [V*8]
    const int* __restrict__ nidx,   // [V,32]
    float* __restrict__ out,        // [V,144]
    int V)
{
  __shared__ int sidx[V_PER_BLOCK][K_N + 1];   // stride 33: conflict-free

  const int tid = threadIdx.x;
  const int block_v0 = blockIdx.x * V_PER_BLOCK;

  {
    const long long base = (long long)block_v0 * K_N;
    const long long avail = (long long)V * K_N - base;
    #pragma unroll
    for (int i = tid; i < V_PER_BLOCK * K_N; i += THREADS) {
      int val = (i < avail) ? __builtin_nontemporal_load(nidx + base + i) : 0;
      sidx[i / K_N][i % K_N] = val;
    }
  }
  __syncthreads();

  const int vloc = tid >> 2;        // vertex within block
  const int t    = tid & 3;         // feature quad owner
  const int v    = block_v0 + vloc;
  if (v >= V) return;

  const int half_off = (t >> 1) * 4;  // 16B half holding my quad
  const bool hi_word = (t & 1);       // word within the half: .x or .z

  v2f a0[4], a1[4], a2[4], a3[4], a4[4];
  #pragma unroll
  for (int j = 0; j < 4; ++j) {
    a0[j] = (v2f){0.f, 0.f};
    a1[j] = (v2f){0.f, 0.f};
    a2[j] = (v2f){0.f, 0.f};
    a3[j] = (v2f){0.f, 0.f};
    a4[j] = (v2f){0.f, 0.f};
  }

  #pragma unroll
  for (int kb = 0; kb < K_N; kb += BATCH) {
    v4u r[BATCH];
    #pragma unroll
    for (int u = 0; u < BATCH; ++u) {
      const int idx = sidx[vloc][kb + u];
      r[u] = *reinterpret_cast<const v4u*>(rec + (size_t)idx * REC_DW + half_off);
    }
    #pragma unroll
    for (int u = 0; u < BATCH; ++u) {
      float x0, x1, x2, zpad;
      unpack_h2(r[u].y, x0, x1);
      unpack_h2(r[u].w, x2, zpad);

      const v2f p0 = {1.0f, x0};
      const v2f p1 = {x1, x2};
      const v2f p2 = (v2f){x0, x1} * (v2f){x0, x0};   // (xx00, xx10)
      const v2f p3 = (v2f){x1, x2} * (v2f){x1, x0};   // (xx11, xx20)
      const v2f p4 = (v2f){x2, x2} * (v2f){x1, x2};   // (xx21, xx22)

      const u32 q = hi_word ? r[u].z : r[u].x;
      const float wv[4] = {(float)(q & 0xffu), (float)((q >> 8) & 0xffu),
                           (float)((q >> 16) & 0xffu), (float)(q >> 24)};
      #pragma unroll
      for (int j = 0; j < 4; ++j) {
        const v2f w2 = {wv[j], wv[j]};
        a0[j] = w2 * p0 + a0[j];   // v_pk_fma_f32
        a1[j] = w2 * p1 + a1[j];
        a2[j] = w2 * p2 + a2[j];
        a3[j] = w2 * p3 + a3[j];
        a4[j] = w2 * p4 + a4[j];
      }
    }
  }

  // Epilogue. Raw counts: s = 255*wsum; iw scale cancels with EPS*255.
  float cov[24];
  float mn[12];
  #pragma unroll
  for (int j = 0; j < 4; ++j) {
    const float s   = a0[j].x;
    const float wx0 = a0[j].y;
    const float wx1 = a1[j].x;
    const float wx2 = a1[j].y;
    const float e00 = a2[j].x;
    const float e10 = a2[j].y;
    const float e11 = a3[j].x;
    const float e20 = a3[j].y;
    const float e21 = a4[j].x;
    const float e22 = a4[j].y;
    const float iw = 1.0f / (s + 255.0f * EPS);
    const float m0 = wx0 * iw;
    const float m1 = wx1 * iw;
    const float m2 = wx2 * iw;
    cov[j * 6 + 0] = fmaf(-m0, m0, e00 * iw);
    cov[j * 6 + 1] = fmaf(-m1, m0, e10 * iw);
    cov[j * 6 + 2] = fmaf(-m1, m1, e11 * iw);
    cov[j * 6 + 3] = fmaf(-m2, m0, e20 * iw);
    cov[j * 6 + 4] = fmaf(-m2, m1, e21 * iw);
    cov[j * 6 + 5] = fmaf(-m2, m2, e22 * iw);
    mn[j * 3 + 0] = m0;
    mn[j * 3 + 1] = m1;
    mn[j * 3 + 2] = m2;
  }

  // Normal cached float4 stores (L2 write-combines). All 16B-aligned.
  float* outv = out + (size_t)v * 144;
  v4f* cdst = reinterpret_cast<v4f*>(outv + t * 24);       // 24 floats
  const v4f* csrc = reinterpret_cast<const v4f*>(cov);
  #pragma unroll
  for (int q2 = 0; q2 < 6; ++q2) cdst[q2] = csrc[q2];
  v4f* mdst = reinterpret_cast<v4f*>(outv + 96 + t * 12);  // 12 floats
  const v4f* msrc = reinterpret_cast<const v4f*>(mn);
  #pragma unroll
  for (int q2 = 0; q2 < 3; ++q2) mdst[q2] = msrc[q2];
}

// ---------------------------------------------------------------------------
// Fallback (no workspace): f32 path.
// ---------------------------------------------------------------------------
__global__ __launch_bounds__(256) void neigh_cov_f_kernel(
    const float* __restrict__ coords,
    const float* __restrict__ feats,
    const int*   __restrict__ nidx,
    float*       __restrict__ out,
    int V)
{
  __shared__ int sidx[64][K_N + 1];
  const int tid = threadIdx.x;
  const int block_v0 = blockIdx.x * 64;
  {
    const long long base = (long long)block_v0 * K_N;
    const long long avail = (long long)V * K_N - base;
    for (int i = tid; i < 64 * K_N; i += 256) {
      int val = (i < avail) ? nidx[base + i] : 0;
      sidx[i / K_N][i % K_N] = val;
    }
  }
  __syncthreads();
  const int vloc = tid >> 2, t = tid & 3;
  const int v = block_v0 + vloc;
  if (v >= V) return;
  float s[4] = {0,0,0,0}, wx0[4] = {0,0,0,0}, wx1[4] = {0,0,0,0}, wx2[4] = {0,0,0,0};
  float e00[4] = {0,0,0,0}, e10[4] = {0,0,0,0}, e11[4] = {0,0,0,0};
  float e20[4] = {0,0,0,0}, e21[4] = {0,0,0,0}, e22[4] = {0,0,0,0};
  #pragma unroll 4
  for (int k = 0; k < K_N; ++k) {
    const int idx = sidx[vloc][k];
    const v4f w4 = *reinterpret_cast<const v4f*>(feats + (size_t)idx * F_DIM + t * 4);
    const float x0 = coords[(size_t)idx * C_DIM + 0];
    const float x1 = coords[(size_t)idx * C_DIM + 1];
    const float x2 = coords[(size_t)idx * C_DIM + 2];
    const float xx00 = x0*x0, xx10 = x1*x0, xx11 = x1*x1;
    const float xx20 = x2*x0, xx21 = x2*x1, xx22 = x2*x2;
    const float wv[4] = {w4.x, w4.y, w4.z, w4.w};
    #pragma unroll
    for (int j = 0; j < 4; ++j) {
      const float w = wv[j];
      s[j] += w;
      wx0[j] = fmaf(w, x0, wx0[j]); wx1[j] = fmaf(w, x1, wx1[j]); wx2[j] = fmaf(w, x2, wx2[j]);
      e00[j] = fmaf(w, xx00, e00[j]); e10[j] = fmaf(w, xx10, e10[j]); e11[j] = fmaf(w, xx11, e11[j]);
      e20[j] = fmaf(w, xx20, e20[j]); e21[j] = fmaf(w, xx21, e21[j]); e22[j] = fmaf(w, xx22, e22[j]);
    }
  }
  float cov[24], mn[12];
  #pragma unroll
  for (int j = 0; j < 4; ++j) {
    const float iw = 1.0f / (s[j] + EPS);
    const float m0 = wx0[j]*iw, m1 = wx1[j]*iw, m2 = wx2[j]*iw;
    cov[j*6+0] = fmaf(-m0, m0, e00[j]*iw);
    cov[j*6+1] = fmaf(-m1, m0, e10[j]*iw);
    cov[j*6+2] = fmaf(-m1, m1, e11[j]*iw);
    cov[j*6+3] = fmaf(-m2, m0, e20[j]*iw);
    cov[j*6+4] = fmaf(-m2, m1, e21[j]*iw);
    cov[j*6+5] = fmaf(-m2, m2, e22[j]*iw);
    mn[j*3+0] = m0; mn[j*3+1] = m1; mn[j*3+2] = m2;
  }
  float* outv = out + (size_t)v * 144;
  v4f* cdst = reinterpret_cast<v4f*>(outv + t * 24);
  const v4f* csrc = reinterpret_cast<const v4f*>(cov);
  #pragma unroll
  for (int q = 0; q < 6; ++q) cdst[q] = csrc[q];
  v4f* mdst = reinterpret_cast<v4f*>(outv + 96 + t * 12);
  const v4f* msrc = reinterpret_cast<const v4f*>(mn);
  #pragma unroll
  for (int q = 0; q < 3; ++q) mdst[q] = msrc[q];
}

extern "C" void kernel_launch(void* const* d_in, const int* in_sizes, int n_in,
                              void* d_out, int out_size, void* d_ws, size_t ws_size,
                              hipStream_t stream) {
  const float* coords = (const float*)d_in[0];
  const float* feats  = (const float*)d_in[1];
  const int*   nidx   = (const int*)d_in[2];
  float* out = (float*)d_out;

  const int V = in_sizes[0] / C_DIM;   // 200000
  const int blocks = (V + V_PER_BLOCK - 1) / V_PER_BLOCK;

  const size_t rec_bytes = (size_t)V * REC_DW * 4;   // 6.4 MB
  const bool use_rec = (d_ws != nullptr) && (ws_size >= rec_bytes);

  if (use_rec) {
    u32* rec = (u32*)d_ws;
    pack_rec_kernel<<<(V + 63) / 64, 256, 0, stream>>>(coords, feats, rec, V);
    neigh_cov_r_kernel<<<blocks, THREADS, 0, stream>>>(rec, nidx, out, V);
  } else {
    neigh_cov_f_kernel<<<(V + 63) / 64, 256, 0, stream>>>(coords, feats, nidx, out, V);
  }
}